// Round 10
// baseline (205.362 us; speedup 1.0000x reference)
//
#include <hip/hip_runtime.h>

#define NPTS  131072        // B*G
#define GPTS  32768         // G

typedef __attribute__((ext_vector_type(4)))  _Float16 half4v;
typedef __attribute__((ext_vector_type(8)))  _Float16 half8v;
typedef __attribute__((ext_vector_type(16))) float    f32x16;

// ---- sigmoid emulating the reference f32 pipeline (bit-faithful) ----------
__device__ __forceinline__ float sigf(float x) {
    x = fminf(fmaxf(x, -9.21f), 9.21f);
    float t = (float)exp(-(double)x);
    return 1.0f / (1.0f + t);
}

// ---- fused front-end -------------------------------------------------------
// blocks [0,512):    sigmoid + per-block min + clears (grid, tile-hist)
// blocks [512,530):  W -> 32x32x16 f16 B-fragments
// blocks [530,2578): feats f32 -> f16 rows
__global__ __launch_bounds__(256) void k_front(const float* __restrict__ anchor,
                                               const float* __restrict__ W,
                                               const float* __restrict__ feats,
                                               float* __restrict__ s0a,
                                               float* __restrict__ s1a,
                                               float2* __restrict__ blockmin,
                                               _Float16* __restrict__ bpk,
                                               _Float16* __restrict__ fb,
                                               int* __restrict__ grd,
                                               int* __restrict__ thist) {
    const int bid = blockIdx.x;
    if (bid < 512) {
        __shared__ float red[8];
        int i = bid * 256 + threadIdx.x;            // [0,131072)
        int2 mone = {-1, -1};
        ((int2*)grd)[i] = mone;                     // clear 1 MB rulebook grid
        if (i < 1024) thist[i] = 0;                 // clear tile histogram
        float2 a = ((const float2*)anchor)[i];
        float s0 = sigf(a.x);
        float s1 = sigf(a.y);
        s0a[i] = s0;
        s1a[i] = s1;
        float m0 = s0, m1 = s1;
        #pragma unroll
        for (int off = 32; off; off >>= 1) {
            m0 = fminf(m0, __shfl_down(m0, off));
            m1 = fminf(m1, __shfl_down(m1, off));
        }
        int wv = threadIdx.x >> 6;
        if ((threadIdx.x & 63) == 0) { red[wv * 2] = m0; red[wv * 2 + 1] = m1; }
        __syncthreads();
        if (threadIdx.x == 0) {
            float a0 = fminf(fminf(red[0], red[2]), fminf(red[4], red[6]));
            float a1 = fminf(fminf(red[1], red[3]), fminf(red[5], red[7]));
            blockmin[bid] = make_float2(a0, a1);
        }
    } else if (bid < 530) {
        // frag q = t*8 + ks*2 + nt; lane l: B[k=ks*16+(l>>5)*8+j][n=nt*32+(l&31)]
        int tid = (bid - 512) * 256 + threadIdx.x;
        if (tid >= 4608) return;
        int l  = tid & 63;
        int q  = tid >> 6;
        int nt = q & 1;
        int ks = (q >> 1) & 3;
        int t  = q >> 3;
        int n  = nt * 32 + (l & 31);
        int kb = ks * 16 + (l >> 5) * 8;
        half8v v;
        #pragma unroll
        for (int j = 0; j < 8; ++j)
            v[j] = (_Float16)W[(t * 64 + kb + j) * 64 + n];
        ((half8v*)bpk)[q * 64 + l] = v;
    } else {
        int tid = (bid - 530) * 256 + threadIdx.x;  // [0,524288)
        #pragma unroll
        for (int r = 0; r < 4; ++r) {
            long i = tid + (long)r * 524288;        // 2,097,152 float4 total
            float4 f = ((const float4*)feats)[i];
            half4v o = {(_Float16)f.x, (_Float16)f.y, (_Float16)f.z, (_Float16)f.w};
            *(half4v*)(fb + i * 4) = o;
        }
    }
}

// ---- cell index + rulebook scatter (max id wins) + tile histogram ----------
__global__ __launch_bounds__(256) void k_grid(const float* __restrict__ s0a,
                                              const float* __restrict__ s1a,
                                              const float2* __restrict__ blockmin,
                                              int* __restrict__ pidx,
                                              int* __restrict__ grid,
                                              int* __restrict__ thist) {
    __shared__ float red[8];
    float2 ba = blockmin[threadIdx.x];
    float2 bb = blockmin[threadIdx.x + 256];
    float m0 = fminf(ba.x, bb.x), m1 = fminf(ba.y, bb.y);
    #pragma unroll
    for (int off = 32; off; off >>= 1) {
        m0 = fminf(m0, __shfl_down(m0, off));
        m1 = fminf(m1, __shfl_down(m1, off));
    }
    int wv = threadIdx.x >> 6;
    if ((threadIdx.x & 63) == 0) { red[wv * 2] = m0; red[wv * 2 + 1] = m1; }
    __syncthreads();
    m0 = fminf(fminf(red[0], red[2]), fminf(red[4], red[6]));
    m1 = fminf(fminf(red[1], red[3]), fminf(red[5], red[7]));

    int i = blockIdx.x * 256 + threadIdx.x;
    int iy = (int)((s0a[i] - m0) * 256.0f);
    int ix = (int)((s1a[i] - m1) * 256.0f);
    pidx[i] = (iy << 8) | ix;
    int b = i >> 15;
    atomicMax(&grid[(b << 16) + (iy << 8) + ix], i);
    int tile = (b << 8) | ((iy >> 4) << 4) | (ix >> 4);
    atomicAdd(&thist[tile], 1);
}

// ---- exclusive scan over 1024 tile counts (single block) -------------------
__global__ __launch_bounds__(256) void k_scan(const int* __restrict__ thist,
                                              int* __restrict__ tstart,
                                              int* __restrict__ tcur) {
    __shared__ int sd[256];
    int tid = threadIdx.x;
    int4 h = ((const int4*)thist)[tid];
    int s = h.x + h.y + h.z + h.w;
    sd[tid] = s;
    __syncthreads();
    #pragma unroll
    for (int off = 1; off < 256; off <<= 1) {
        int v = (tid >= off) ? sd[tid - off] : 0;
        __syncthreads();
        sd[tid] += v;
        __syncthreads();
    }
    int excl = sd[tid] - s;
    int4 o;
    o.x = excl; o.y = o.x + h.x; o.z = o.y + h.y; o.w = o.z + h.z;
    ((int4*)tstart)[tid] = o;
    ((int4*)tcur)[tid]   = o;
    if (tid == 255) tstart[1024] = sd[255];
}

// ---- scatter point indices into tile-sorted order (indices only, 4 B) ------
__global__ __launch_bounds__(256) void k_tscat(const int* __restrict__ pidx,
                                               int* __restrict__ tcur,
                                               int* __restrict__ tlist) {
    int i = blockIdx.x * 256 + threadIdx.x;
    int pk = pidx[i];
    int iy = pk >> 8, ix = pk & 255;
    int b = i >> 15;
    int tile = (b << 8) | ((iy >> 4) << 4) | (ix >> 4);
    int slot = atomicAdd(&tcur[tile], 1);
    // pack point id + local cell coords (ly,lx in [0,16))
    tlist[slot] = i | ((iy & 15) << 17) | ((ix & 15) << 21);
}

// ---- MFMA conv: block = 16x16-cell tile; 18x18 halo rows staged in LDS -----
// Each halo winner row loaded from global ONCE per tile (A-traffic 151->42 MB).
// LDS rows XOR-swizzled (16B unit q stored at q^(row&7)) to break the 128B-
// stride bank conflict (G4). A-frag: lane l holds A[row=l&31][k=ks*16+(l>>5)*8+j].
// C/D: col=lane&31, row=(reg&3)+8*(reg>>2)+4*(lane>>5)   [HW-verified]
__global__ __launch_bounds__(256, 3) void k_mconv(const _Float16* __restrict__ fb,
                                                  const _Float16* __restrict__ bpk,
                                                  const int* __restrict__ grid,
                                                  const int* __restrict__ tstart,
                                                  const int* __restrict__ tlist,
                                                  float* __restrict__ out) {
    __shared__ half8v bsh[2592];                    // 324 rows * 8 * 16B = 41.5 KB

    const int bid = blockIdx.x;
    const int b  = bid >> 8;
    const int ty = (bid >> 4) & 15;
    const int tx = bid & 15;

    // stage 18x18 halo winner rows (zeros for empty/OOB cells)
    for (int s = threadIdx.x; s < 324; s += 256) {
        int hy = (ty << 4) - 1 + s / 18;
        int hx = (tx << 4) - 1 + s % 18;
        int nid = -1;
        if ((unsigned)hy < 256u && (unsigned)hx < 256u)
            nid = grid[(b << 16) + (hy << 8) + hx];
        half8v* dst = &bsh[s * 8];
        int sw = s & 7;
        if (nid >= 0) {
            const half8v* src = (const half8v*)(fb + ((long)nid << 6));
            #pragma unroll
            for (int q = 0; q < 8; ++q) dst[q ^ sw] = src[q];
        } else {
            half8v z = {};
            #pragma unroll
            for (int q = 0; q < 8; ++q) dst[q] = z;
        }
    }

    const int tb = tstart[bid];
    const int np = tstart[bid + 1] - tb;
    __syncthreads();
    if (np == 0) return;

    const int lane  = threadIdx.x & 63;
    const int wv    = threadIdx.x >> 6;
    const int prow  = lane & 31;
    const int khalf = lane >> 5;
    const half8v* bq = (const half8v*)bpk + lane;

    for (int base = wv * 32; base < np; base += 128) {
        const int npw = np - base;                   // valid outputs this chunk
        const int myi = base + prow;
        const int e = tlist[tb + ((myi < np) ? myi : np - 1)];
        const int ly = ((e >> 17) & 15) + 1;
        const int lx = ((e >> 21) & 15) + 1;

        f32x16 acc0, acc1;
        #pragma unroll
        for (int r = 0; r < 16; ++r) { acc0[r] = 0.0f; acc1[r] = 0.0f; }

        #pragma unroll
        for (int t = 0; t < 9; ++t) {
            const int r  = (ly + t / 3 - 1) * 18 + (lx + t % 3 - 1);
            const int rb = r * 8;
            const int sw = r & 7;
            half8v a0 = bsh[rb + ((0 + khalf) ^ sw)];
            half8v a1 = bsh[rb + ((2 + khalf) ^ sw)];
            half8v a2 = bsh[rb + ((4 + khalf) ^ sw)];
            half8v a3 = bsh[rb + ((6 + khalf) ^ sw)];
            const half8v* bt = bq + (t << 9);        // 8 frags * 64 lanes per tap
            acc0 = __builtin_amdgcn_mfma_f32_32x32x16_f16(a0, bt[0 * 64], acc0, 0, 0, 0);
            acc1 = __builtin_amdgcn_mfma_f32_32x32x16_f16(a0, bt[1 * 64], acc1, 0, 0, 0);
            acc0 = __builtin_amdgcn_mfma_f32_32x32x16_f16(a1, bt[2 * 64], acc0, 0, 0, 0);
            acc1 = __builtin_amdgcn_mfma_f32_32x32x16_f16(a1, bt[3 * 64], acc1, 0, 0, 0);
            acc0 = __builtin_amdgcn_mfma_f32_32x32x16_f16(a2, bt[4 * 64], acc0, 0, 0, 0);
            acc1 = __builtin_amdgcn_mfma_f32_32x32x16_f16(a2, bt[5 * 64], acc1, 0, 0, 0);
            acc0 = __builtin_amdgcn_mfma_f32_32x32x16_f16(a3, bt[6 * 64], acc0, 0, 0, 0);
            acc1 = __builtin_amdgcn_mfma_f32_32x32x16_f16(a3, bt[7 * 64], acc1, 0, 0, 0);
        }

        #pragma unroll
        for (int r = 0; r < 16; ++r) {
            int pr = (r & 3) + ((r >> 2) << 3) + (khalf << 2);
            if (pr < npw) {
                int op = tlist[tb + base + pr] & 0x1FFFF;
                out[(long)op * 64 + prow]      = acc0[r];
                out[(long)op * 64 + 32 + prow] = acc1[r];
            }
        }
    }
}

extern "C" void kernel_launch(void* const* d_in, const int* in_sizes, int n_in,
                              void* d_out, int out_size, void* d_ws, size_t ws_size,
                              hipStream_t stream) {
    const float* inst   = (const float*)d_in[0]; // (B,G,64)
    const float* anchor = (const float*)d_in[1]; // (B,G,2)
    const float* W      = (const float*)d_in[2]; // (3,3,64,64)
    float* out = (float*)d_out;

    char* ws = (char*)d_ws;
    float*     s0a    = (float*)(ws);                    // 512 KB
    float*     s1a    = (float*)(ws + 524288);           // 512 KB
    int*       pidx   = (int*)(ws + 1048576);            // 512 KB
    int*       grd    = (int*)(ws + 1572864);            // 1 MB
    float2*    bmin   = (float2*)(ws + 2621440);         // 4 KB
    int*       thist  = (int*)(ws + 2625536);            // 4 KB
    int*       tstart = (int*)(ws + 2629632);            // 4.1 KB (1025)
    int*       tcur   = (int*)(ws + 2637824);            // 4 KB
    int*       tlist  = (int*)(ws + 2641920);            // 512 KB
    _Float16*  fb     = (_Float16*)(ws + 3166208);       // N*64 f16 = 16.78 MB
    _Float16*  bpk    = (_Float16*)(ws + 19943424);      // 72 KB

    k_front<<<2578, 256, 0, stream>>>(anchor, W, inst, s0a, s1a, bmin, bpk, fb, grd, thist);
    k_grid <<<512,  256, 0, stream>>>(s0a, s1a, bmin, pidx, grd, thist);
    k_scan <<<1,    256, 0, stream>>>(thist, tstart, tcur);
    k_tscat<<<512,  256, 0, stream>>>(pidx, tcur, tlist);
    k_mconv<<<1024, 256, 0, stream>>>(fb, bpk, grd, tstart, tlist, out);
}

// Round 11
// 55.715 us; speedup vs baseline: 3.6859x; 3.6859x over previous
//
#include <hip/hip_runtime.h>

#define NPTS  131072        // B*G
#define GPTS  32768         // G

typedef __attribute__((ext_vector_type(4)))  _Float16 half4v;
typedef __attribute__((ext_vector_type(8)))  _Float16 half8v;
typedef __attribute__((ext_vector_type(16))) float    f32x16;

// ---- sigmoid emulating the reference f32 pipeline (bit-faithful) ----------
__device__ __forceinline__ float sigf(float x) {
    x = fminf(fmaxf(x, -9.21f), 9.21f);
    float t = (float)exp(-(double)x);
    return 1.0f / (1.0f + t);
}

// ---- fused front-end -------------------------------------------------------
// blocks [0,512):    sigmoid + per-block min + grid clear
// blocks [512,530):  W -> 32x32x16 f16 B-fragments
// blocks [530,2578): feats f32 -> f16 rows (+1 zero row)
__global__ __launch_bounds__(256) void k_front(const float* __restrict__ anchor,
                                               const float* __restrict__ W,
                                               const float* __restrict__ feats,
                                               float* __restrict__ s0a,
                                               float* __restrict__ s1a,
                                               float2* __restrict__ blockmin,
                                               _Float16* __restrict__ bpk,
                                               _Float16* __restrict__ fb,
                                               int* __restrict__ grd) {
    const int bid = blockIdx.x;
    if (bid < 512) {
        __shared__ float red[8];
        int i = bid * 256 + threadIdx.x;            // [0,131072)
        int2 mone = {-1, -1};
        ((int2*)grd)[i] = mone;                     // clear 1 MB rulebook grid
        float2 a = ((const float2*)anchor)[i];
        float s0 = sigf(a.x);
        float s1 = sigf(a.y);
        s0a[i] = s0;
        s1a[i] = s1;
        float m0 = s0, m1 = s1;
        #pragma unroll
        for (int off = 32; off; off >>= 1) {
            m0 = fminf(m0, __shfl_down(m0, off));
            m1 = fminf(m1, __shfl_down(m1, off));
        }
        int wv = threadIdx.x >> 6;
        if ((threadIdx.x & 63) == 0) { red[wv * 2] = m0; red[wv * 2 + 1] = m1; }
        __syncthreads();
        if (threadIdx.x == 0) {
            float a0 = fminf(fminf(red[0], red[2]), fminf(red[4], red[6]));
            float a1 = fminf(fminf(red[1], red[3]), fminf(red[5], red[7]));
            blockmin[bid] = make_float2(a0, a1);
        }
    } else if (bid < 530) {
        // frag q = t*8 + ks*2 + nt; lane l: B[k=ks*16+(l>>5)*8+j][n=nt*32+(l&31)]
        int tid = (bid - 512) * 256 + threadIdx.x;
        if (tid >= 4608) return;
        int l  = tid & 63;
        int q  = tid >> 6;
        int nt = q & 1;
        int ks = (q >> 1) & 3;
        int t  = q >> 3;
        int n  = nt * 32 + (l & 31);
        int kb = ks * 16 + (l >> 5) * 8;
        half8v v;
        #pragma unroll
        for (int j = 0; j < 8; ++j)
            v[j] = (_Float16)W[(t * 64 + kb + j) * 64 + n];
        ((half8v*)bpk)[q * 64 + l] = v;
    } else {
        int tid = (bid - 530) * 256 + threadIdx.x;  // [0,524288)
        if (bid == 530 && threadIdx.x < 8) {        // zero row NPTS
            half8v z = {};
            *(half8v*)(fb + (long)NPTS * 64 + threadIdx.x * 8) = z;
        }
        #pragma unroll
        for (int r = 0; r < 4; ++r) {
            long i = tid + (long)r * 524288;        // 2,097,152 float4 total
            float4 f = ((const float4*)feats)[i];
            half4v o = {(_Float16)f.x, (_Float16)f.y, (_Float16)f.z, (_Float16)f.w};
            *(half4v*)(fb + i * 4) = o;
        }
    }
}

// ---- cell index + rulebook scatter (max id wins); min-fold at head --------
__global__ __launch_bounds__(256) void k_grid(const float* __restrict__ s0a,
                                              const float* __restrict__ s1a,
                                              const float2* __restrict__ blockmin,
                                              int* __restrict__ pidx,
                                              int* __restrict__ grid) {
    __shared__ float red[8];
    float2 ba = blockmin[threadIdx.x];
    float2 bb = blockmin[threadIdx.x + 256];
    float m0 = fminf(ba.x, bb.x), m1 = fminf(ba.y, bb.y);
    #pragma unroll
    for (int off = 32; off; off >>= 1) {
        m0 = fminf(m0, __shfl_down(m0, off));
        m1 = fminf(m1, __shfl_down(m1, off));
    }
    int wv = threadIdx.x >> 6;
    if ((threadIdx.x & 63) == 0) { red[wv * 2] = m0; red[wv * 2 + 1] = m1; }
    __syncthreads();
    m0 = fminf(fminf(red[0], red[2]), fminf(red[4], red[6]));
    m1 = fminf(fminf(red[1], red[3]), fminf(red[5], red[7]));

    int i = blockIdx.x * 256 + threadIdx.x;
    int iy = (int)((s0a[i] - m0) * 256.0f);
    int ix = (int)((s1a[i] - m1) * 256.0f);
    pidx[i] = (iy << 8) | ix;
    int b = i >> 15;
    atomicMax(&grid[(b << 16) + (iy << 8) + ix], i);
}

// ---- MFMA conv, tap-split: wave = 32 points x 64 couts x HALF the taps -----
// Block = 4 waves = 2 point-tiles x 2 tap-halves (taps 0-4 / 5-8). Partial
// sums merged via LDS ([r][lane] layout, conflict-free); wave 0 of each pair
// does the final COALESCED store (original point order). Grid = 2048 blocks,
// (256,6) -> ~24 waves/CU (2x R9's 12) to hide random-gather latency.
// A-frag: lane l holds A[row=l&31][k=ks*16+(l>>5)*8+j].
// C/D: col=lane&31, row=(reg&3)+8*(reg>>2)+4*(lane>>5)   [HW-verified]
__global__ __launch_bounds__(256, 6) void k_mconv(const _Float16* __restrict__ fb,
                                                  const _Float16* __restrict__ bpk,
                                                  const int* __restrict__ pidx,
                                                  const int* __restrict__ grid,
                                                  float* __restrict__ out) {
    __shared__ float lred[2][32][64];               // 16 KB

    const int lane  = threadIdx.x & 63;
    const int wv    = threadIdx.x >> 6;             // 0..3
    const int half  = wv & 1;                       // tap half
    const int tile  = wv >> 1;                      // 0..1
    const int pbase = (blockIdx.x << 6) + (tile << 5);
    const int prow  = lane & 31;
    const int khalf = lane >> 5;
    const int p     = pbase + prow;

    const int pk = pidx[p];
    const int iy = pk >> 8;
    const int ix = pk & 255;
    const int* gb = grid + ((p >> 15) << 16);

    const int t0 = half ? 5 : 0;
    const int nt = half ? 4 : 5;

    int nid[5];
    #pragma unroll
    for (int u = 0; u < 5; ++u) {
        if (u < nt) {
            const int t  = t0 + u;
            const int ny = iy + t / 3 - 1;
            const int nx = ix + t % 3 - 1;
            int n = ((unsigned)ny < 256u && (unsigned)nx < 256u) ? gb[(ny << 8) + nx] : -1;
            nid[u] = (n < 0) ? NPTS : n;            // zero row for invalid taps
        } else {
            nid[u] = NPTS;
        }
    }

    const half8v* bq = (const half8v*)bpk + lane;

    f32x16 acc0, acc1;
    #pragma unroll
    for (int r = 0; r < 16; ++r) { acc0[r] = 0.0f; acc1[r] = 0.0f; }

    #pragma unroll
    for (int u = 0; u < 5; ++u) {
        if (u < nt) {
            const int t = t0 + u;
            const half8v* arow = (const half8v*)(fb + ((long)nid[u] << 6));
            half8v a0 = arow[khalf];
            half8v a1 = arow[2 + khalf];
            half8v a2 = arow[4 + khalf];
            half8v a3 = arow[6 + khalf];
            const half8v* bt = bq + (t << 9);       // 8 frags * 64 lanes per tap
            acc0 = __builtin_amdgcn_mfma_f32_32x32x16_f16(a0, bt[0 * 64], acc0, 0, 0, 0);
            acc1 = __builtin_amdgcn_mfma_f32_32x32x16_f16(a0, bt[1 * 64], acc1, 0, 0, 0);
            acc0 = __builtin_amdgcn_mfma_f32_32x32x16_f16(a1, bt[2 * 64], acc0, 0, 0, 0);
            acc1 = __builtin_amdgcn_mfma_f32_32x32x16_f16(a1, bt[3 * 64], acc1, 0, 0, 0);
            acc0 = __builtin_amdgcn_mfma_f32_32x32x16_f16(a2, bt[4 * 64], acc0, 0, 0, 0);
            acc1 = __builtin_amdgcn_mfma_f32_32x32x16_f16(a2, bt[5 * 64], acc1, 0, 0, 0);
            acc0 = __builtin_amdgcn_mfma_f32_32x32x16_f16(a3, bt[6 * 64], acc0, 0, 0, 0);
            acc1 = __builtin_amdgcn_mfma_f32_32x32x16_f16(a3, bt[7 * 64], acc1, 0, 0, 0);
        }
    }

    // merge tap-halves: half==1 deposits, half==0 adds and stores (coalesced)
    if (half) {
        #pragma unroll
        for (int r = 0; r < 16; ++r) {
            lred[tile][r][lane]      = acc0[r];
            lred[tile][16 + r][lane] = acc1[r];
        }
    }
    __syncthreads();
    if (!half) {
        #pragma unroll
        for (int r = 0; r < 16; ++r) {
            float v0 = acc0[r] + lred[tile][r][lane];
            float v1 = acc1[r] + lred[tile][16 + r][lane];
            int orow = pbase + (r & 3) + ((r >> 2) << 3) + (khalf << 2);
            out[(long)orow * 64 + prow]      = v0;
            out[(long)orow * 64 + 32 + prow] = v1;
        }
    }
}

extern "C" void kernel_launch(void* const* d_in, const int* in_sizes, int n_in,
                              void* d_out, int out_size, void* d_ws, size_t ws_size,
                              hipStream_t stream) {
    const float* inst   = (const float*)d_in[0]; // (B,G,64)
    const float* anchor = (const float*)d_in[1]; // (B,G,2)
    const float* W      = (const float*)d_in[2]; // (3,3,64,64)
    float* out = (float*)d_out;

    char* ws = (char*)d_ws;
    float*     s0a  = (float*)(ws);                      // 512 KB
    float*     s1a  = (float*)(ws + 524288);             // 512 KB
    int*       pidx = (int*)(ws + 1048576);              // 512 KB
    int*       grd  = (int*)(ws + 1572864);              // 1 MB
    float2*    bmin = (float2*)(ws + 2621440);           // 4 KB (512 float2)
    _Float16*  fb   = (_Float16*)(ws + 2625536);         // (N+1)*64 f16
    _Float16*  bpk  = (_Float16*)(ws + 19402880);        // 72 KB

    k_front<<<2578, 256, 0, stream>>>(anchor, W, inst, s0a, s1a, bmin, bpk, fb, grd);
    k_grid <<<512,  256, 0, stream>>>(s0a, s1a, bmin, pidx, grd);
    k_mconv<<<2048, 256, 0, stream>>>(fb, bpk, pidx, grd, out);
}

// Round 12
// 46.897 us; speedup vs baseline: 4.3790x; 1.1880x over previous
//
#include <hip/hip_runtime.h>

#define NPTS  131072        // B*G
#define GPTS  32768         // G

typedef __attribute__((ext_vector_type(4)))  _Float16 half4v;
typedef __attribute__((ext_vector_type(8)))  _Float16 half8v;
typedef __attribute__((ext_vector_type(16))) float    f32x16;

// ---- sigmoid emulating the reference f32 pipeline (bit-faithful) ----------
__device__ __forceinline__ float sigf(float x) {
    x = fminf(fmaxf(x, -9.21f), 9.21f);
    float t = (float)exp(-(double)x);
    return 1.0f / (1.0f + t);
}

// ---- fused front-end -------------------------------------------------------
// blocks [0,512):    sigmoid + per-block min + grid clear
// blocks [512,530):  W -> 32x32x16 f16 B-fragments
// blocks [530,2578): feats f32 -> f16 rows (+1 zero row)
__global__ __launch_bounds__(256) void k_front(const float* __restrict__ anchor,
                                               const float* __restrict__ W,
                                               const float* __restrict__ feats,
                                               float* __restrict__ s0a,
                                               float* __restrict__ s1a,
                                               float2* __restrict__ blockmin,
                                               _Float16* __restrict__ bpk,
                                               _Float16* __restrict__ fb,
                                               int* __restrict__ grd) {
    const int bid = blockIdx.x;
    if (bid < 512) {
        __shared__ float red[8];
        int i = bid * 256 + threadIdx.x;            // [0,131072)
        int2 mone = {-1, -1};
        ((int2*)grd)[i] = mone;                     // clear 1 MB rulebook grid
        float2 a = ((const float2*)anchor)[i];
        float s0 = sigf(a.x);
        float s1 = sigf(a.y);
        s0a[i] = s0;
        s1a[i] = s1;
        float m0 = s0, m1 = s1;
        #pragma unroll
        for (int off = 32; off; off >>= 1) {
            m0 = fminf(m0, __shfl_down(m0, off));
            m1 = fminf(m1, __shfl_down(m1, off));
        }
        int wv = threadIdx.x >> 6;
        if ((threadIdx.x & 63) == 0) { red[wv * 2] = m0; red[wv * 2 + 1] = m1; }
        __syncthreads();
        if (threadIdx.x == 0) {
            float a0 = fminf(fminf(red[0], red[2]), fminf(red[4], red[6]));
            float a1 = fminf(fminf(red[1], red[3]), fminf(red[5], red[7]));
            blockmin[bid] = make_float2(a0, a1);
        }
    } else if (bid < 530) {
        // frag q = t*8 + ks*2 + nt; lane l: B[k=ks*16+(l>>5)*8+j][n=nt*32+(l&31)]
        int tid = (bid - 512) * 256 + threadIdx.x;
        if (tid >= 4608) return;
        int l  = tid & 63;
        int q  = tid >> 6;
        int nt = q & 1;
        int ks = (q >> 1) & 3;
        int t  = q >> 3;
        int n  = nt * 32 + (l & 31);
        int kb = ks * 16 + (l >> 5) * 8;
        half8v v;
        #pragma unroll
        for (int j = 0; j < 8; ++j)
            v[j] = (_Float16)W[(t * 64 + kb + j) * 64 + n];
        ((half8v*)bpk)[q * 64 + l] = v;
    } else {
        int tid = (bid - 530) * 256 + threadIdx.x;  // [0,524288)
        if (bid == 530 && threadIdx.x < 8) {        // zero row NPTS
            half8v z = {};
            *(half8v*)(fb + (long)NPTS * 64 + threadIdx.x * 8) = z;
        }
        #pragma unroll
        for (int r = 0; r < 4; ++r) {
            long i = tid + (long)r * 524288;        // 2,097,152 float4 total
            float4 f = ((const float4*)feats)[i];
            half4v o = {(_Float16)f.x, (_Float16)f.y, (_Float16)f.z, (_Float16)f.w};
            *(half4v*)(fb + i * 4) = o;
        }
    }
}

// ---- cell index + rulebook scatter (max id wins); min-fold at head --------
__global__ __launch_bounds__(256) void k_grid(const float* __restrict__ s0a,
                                              const float* __restrict__ s1a,
                                              const float2* __restrict__ blockmin,
                                              int* __restrict__ pidx,
                                              int* __restrict__ grid) {
    __shared__ float red[8];
    float2 ba = blockmin[threadIdx.x];
    float2 bb = blockmin[threadIdx.x + 256];
    float m0 = fminf(ba.x, bb.x), m1 = fminf(ba.y, bb.y);
    #pragma unroll
    for (int off = 32; off; off >>= 1) {
        m0 = fminf(m0, __shfl_down(m0, off));
        m1 = fminf(m1, __shfl_down(m1, off));
    }
    int wv = threadIdx.x >> 6;
    if ((threadIdx.x & 63) == 0) { red[wv * 2] = m0; red[wv * 2 + 1] = m1; }
    __syncthreads();
    m0 = fminf(fminf(red[0], red[2]), fminf(red[4], red[6]));
    m1 = fminf(fminf(red[1], red[3]), fminf(red[5], red[7]));

    int i = blockIdx.x * 256 + threadIdx.x;
    int iy = (int)((s0a[i] - m0) * 256.0f);
    int ix = (int)((s1a[i] - m1) * 256.0f);
    pidx[i] = (iy << 8) | ix;
    int b = i >> 15;
    atomicMax(&grid[(b << 16) + (iy << 8) + ix], i);
}

// ---- MFMA conv with COALESCED A-gathers ------------------------------------
// Wave = 32 points x 64 couts. Per tap: 4 global loads where 8 consecutive
// lanes fetch the 8x16B units of ONE row (full 128B line, HW-coalesced:
// 8 line-requests/instr vs 64 divergent sector-requests before). Rows pass
// through LDS (double-buffered, XOR-swizzled u^(row&7): even 8 lanes/bank).
// Fragments read back are bit-identical to R6's -> same MFMA, same output.
// A-frag: lane l holds A[row=l&31][k=ks*16+(l>>5)*8+j].
// C/D: col=lane&31, row=(reg&3)+8*(reg>>2)+4*(lane>>5)   [HW-verified]
__global__ __launch_bounds__(256, 4) void k_mconv(const _Float16* __restrict__ fb,
                                                  const _Float16* __restrict__ bpk,
                                                  const int* __restrict__ pidx,
                                                  const int* __restrict__ grid,
                                                  float* __restrict__ out) {
    __shared__ int    nidb[4][9][32];               // 4.5 KB
    __shared__ half8v ash[4][2][32][8];             // 32 KB (2-buf staging)

    const int lane  = threadIdx.x & 63;
    const int wv    = threadIdx.x >> 6;
    const int pbase = (blockIdx.x << 7) + (wv << 5);
    const int prow  = lane & 31;
    const int khalf = lane >> 5;

    // precompute all 9 neighbor ids for this wave's 32 points -> LDS
    if (lane < 32) {
        const int p  = pbase + lane;
        const int pk = pidx[p];
        const int iy = pk >> 8;
        const int ix = pk & 255;
        const int* gb = grid + ((p >> 15) << 16);
        #pragma unroll
        for (int t = 0; t < 9; ++t) {
            const int ny = iy + t / 3 - 1;
            const int nx = ix + t % 3 - 1;
            int n = ((unsigned)ny < 256u && (unsigned)nx < 256u) ? gb[(ny << 8) + nx] : -1;
            nidb[wv][t][lane] = (n < 0) ? NPTS : n;  // zero row for invalid taps
        }
    }
    __syncthreads();

    const int g  = lane >> 3;                        // row group 0..7
    const int u  = lane & 7;                         // 16B unit within row
    const int su = u ^ g;                            // swizzled write unit
    const int h  = prow & 7;                         // read-side swizzle key

    const half8v* bq = (const half8v*)bpk + lane;

    f32x16 acc0, acc1;
    #pragma unroll
    for (int r = 0; r < 16; ++r) { acc0[r] = 0.0f; acc1[r] = 0.0f; }

    // prefetch tap 0 rows (coalesced: 8 lanes cover one row's 128B line)
    half8v v0, v1, v2, v3;
    {
        int r0 = nidb[wv][0][g],      r1 = nidb[wv][0][8 + g];
        int r2 = nidb[wv][0][16 + g], r3 = nidb[wv][0][24 + g];
        v0 = ((const half8v*)(fb + ((long)r0 << 6)))[u];
        v1 = ((const half8v*)(fb + ((long)r1 << 6)))[u];
        v2 = ((const half8v*)(fb + ((long)r2 << 6)))[u];
        v3 = ((const half8v*)(fb + ((long)r3 << 6)))[u];
    }

    #pragma unroll
    for (int t = 0; t < 9; ++t) {
        const int buf = t & 1;
        // deposit tap t rows into LDS (swizzled)
        ash[wv][buf][g][su]      = v0;
        ash[wv][buf][8 + g][su]  = v1;
        ash[wv][buf][16 + g][su] = v2;
        ash[wv][buf][24 + g][su] = v3;
        // prefetch tap t+1 (overlaps with MFMAs below)
        if (t < 8) {
            int r0 = nidb[wv][t + 1][g],      r1 = nidb[wv][t + 1][8 + g];
            int r2 = nidb[wv][t + 1][16 + g], r3 = nidb[wv][t + 1][24 + g];
            v0 = ((const half8v*)(fb + ((long)r0 << 6)))[u];
            v1 = ((const half8v*)(fb + ((long)r1 << 6)))[u];
            v2 = ((const half8v*)(fb + ((long)r2 << 6)))[u];
            v3 = ((const half8v*)(fb + ((long)r3 << 6)))[u];
        }
        // fragment reads (un-swizzle): identical data layout to R6's arow[*]
        half8v a0 = ash[wv][buf][prow][(0 + khalf) ^ h];
        half8v a1 = ash[wv][buf][prow][(2 + khalf) ^ h];
        half8v a2 = ash[wv][buf][prow][(4 + khalf) ^ h];
        half8v a3 = ash[wv][buf][prow][(6 + khalf) ^ h];
        const half8v* bt = bq + (t << 9);            // 8 frags * 64 lanes per tap
        acc0 = __builtin_amdgcn_mfma_f32_32x32x16_f16(a0, bt[0 * 64], acc0, 0, 0, 0);
        acc1 = __builtin_amdgcn_mfma_f32_32x32x16_f16(a0, bt[1 * 64], acc1, 0, 0, 0);
        acc0 = __builtin_amdgcn_mfma_f32_32x32x16_f16(a1, bt[2 * 64], acc0, 0, 0, 0);
        acc1 = __builtin_amdgcn_mfma_f32_32x32x16_f16(a1, bt[3 * 64], acc1, 0, 0, 0);
        acc0 = __builtin_amdgcn_mfma_f32_32x32x16_f16(a2, bt[4 * 64], acc0, 0, 0, 0);
        acc1 = __builtin_amdgcn_mfma_f32_32x32x16_f16(a2, bt[5 * 64], acc1, 0, 0, 0);
        acc0 = __builtin_amdgcn_mfma_f32_32x32x16_f16(a3, bt[6 * 64], acc0, 0, 0, 0);
        acc1 = __builtin_amdgcn_mfma_f32_32x32x16_f16(a3, bt[7 * 64], acc1, 0, 0, 0);
    }

    #pragma unroll
    for (int r = 0; r < 16; ++r) {
        int orow = pbase + (r & 3) + ((r >> 2) << 3) + (khalf << 2);
        out[(long)orow * 64 + prow]      = acc0[r];
        out[(long)orow * 64 + 32 + prow] = acc1[r];
    }
}

extern "C" void kernel_launch(void* const* d_in, const int* in_sizes, int n_in,
                              void* d_out, int out_size, void* d_ws, size_t ws_size,
                              hipStream_t stream) {
    const float* inst   = (const float*)d_in[0]; // (B,G,64)
    const float* anchor = (const float*)d_in[1]; // (B,G,2)
    const float* W      = (const float*)d_in[2]; // (3,3,64,64)
    float* out = (float*)d_out;

    char* ws = (char*)d_ws;
    float*     s0a  = (float*)(ws);                      // 512 KB
    float*     s1a  = (float*)(ws + 524288);             // 512 KB
    int*       pidx = (int*)(ws + 1048576);              // 512 KB
    int*       grd  = (int*)(ws + 1572864);              // 1 MB
    float2*    bmin = (float2*)(ws + 2621440);           // 4 KB (512 float2)
    _Float16*  fb   = (_Float16*)(ws + 2625536);         // (N+1)*64 f16
    _Float16*  bpk  = (_Float16*)(ws + 19402880);        // 72 KB

    k_front<<<2578, 256, 0, stream>>>(anchor, W, inst, s0a, s1a, bmin, bpk, fb, grd);
    k_grid <<<512,  256, 0, stream>>>(s0a, s1a, bmin, pidx, grd);
    k_mconv<<<1024, 256, 0, stream>>>(fb, bpk, pidx, grd, out);
}